// Round 14
// baseline (122.179 us; speedup 1.0000x reference)
//
#include <hip/hip_runtime.h>
#include <hip/hip_bf16.h>

// DirectionalSeparableConv2D — round 14: counted-vmcnt pipeline (T4).
// r13 falsified occupancy theory (2x waves -> -1.5%). Real wall: every
// __syncthreads drains vmcnt(0), so each chunk's global_load_lds batch is
// force-drained one phase after issue -> ~1us serial latency x 16 iters x 3
// blocks/CU. Fix: raw s_barrier + counted s_waitcnt vmcnt(3): stage(t+1)'s
// 3 loads stay in flight across the iteration-end barrier and are drained
// only at the next iteration's [B], giving a full-iteration coverage window.
//   iter t: [A] stage(t+1)  [B] vmcnt(3)  [C] s_barrier
//           dwconv(t)+transpose(t-1)  [F] lgkmcnt(0)+s_barrier
// QR=16 -> exactly 3 loads/thread (uniform vmcnt). NT=512. LDS 160000 B.
// sched_barrier(0) fences per rule #18; lgkmcnt(0) before [F] preserves
// LDS visibility that __syncthreads used to provide.

namespace {
constexpr int HH = 48, WW = 48, HW = HH * WW;
constexpr int C_IN = 128, C_OUT = 128, NB = 128;
constexpr int RPB = 8;                  // stripe rows per block
constexpr int NSTR = HH / RPB;          // 6
constexpr int PIX = RPB * WW;           // 384
constexpr int NT = 512;
constexpr int CHK = 8;                  // channels per chunk
constexpr int NCHK = C_IN / CHK;        // 16
constexpr int XR = RPB + 4;             // 12 staged rows
constexpr int QR = 16;                  // quads per staged row (12 data + 4 zero)
constexpr int XQ = CHK * XR * QR;       // 1536 quads = 3 loads/thread exactly
constexpr int XROWF = QR * 4;           // 64 floats per row
constexpr int YCS = 392;                // ycp row stride (ushorts)
constexpr size_t M_BYTES = 128 * 128 * 2;
constexpr size_t ZB_OFF = M_BYTES;
}

typedef __attribute__((ext_vector_type(8))) short bf16x8;
typedef __attribute__((ext_vector_type(4))) float f32x4;

__device__ __forceinline__ ushort f2bf(float f) {
    __hip_bfloat16 h = __float2bfloat16(f);
    return *reinterpret_cast<ushort*>(&h);
}

#define SCHED_FENCE() __builtin_amdgcn_sched_barrier(0)
#define WAIT_VM(N) do { asm volatile("s_waitcnt vmcnt(" #N ")" ::: "memory"); SCHED_FENCE(); } while (0)
#define BAR() do { __builtin_amdgcn_s_barrier(); SCHED_FENCE(); } while (0)
#define WAIT_LGKM() do { asm volatile("s_waitcnt lgkmcnt(0)" ::: "memory"); SCHED_FENCE(); } while (0)

// ======================= k0: build M_bf[o][c] (bf16) =======================
__global__ void build_M(const float* __restrict__ c2c, const float* __restrict__ p2c,
                        const float* __restrict__ d2c, const float* __restrict__ c2d,
                        const float* __restrict__ d2dW, ushort* __restrict__ Mbf) {
    int t = blockIdx.x * 256 + threadIdx.x;
    if (t >= 128 * 128) return;
    int o = t & 127, c = t >> 7;
    float v;
    if (o < 32) {
        if (c < 32)       v = c2c[o * 32 + c];
        else if (c < 56)  v = p2c[o * 24 + c - 32];
        else if (c < 80)  v = p2c[o * 24 + c - 56];
        else if (c < 104) v = d2c[o * 24 + c - 80];
        else              v = d2c[o * 24 + c - 104];
    } else {
        int g = (o - 32) / 24, oo = (o - 32) % 24;
        if (c < 32) v = c2d[oo * 32 + c];
        else {
            int gc = (c - 32) / 24, cc2 = (c - 32) % 24;
            v = (gc == g) ? d2dW[oo * 24 + cc2] : 0.f;
        }
    }
    Mbf[o * 128 + c] = f2bf(v);
}

// ======================= fused kernel =======================
__global__ __launch_bounds__(NT) void dsc_fused(
    const float* __restrict__ x,
    const float* __restrict__ cen_t,   // [32,3,3]
    const float* __restrict__ dir_t,   // [24,5]
    const ushort* __restrict__ Mbf,    // bf16 [128o][128c]
    const float* __restrict__ zb,      // 16B zero block
    float* __restrict__ out)
{
    __shared__ float  xs[2][XQ * 4];        // 2 x 24576 B
    __shared__ ushort yT[PIX * 128];        // 98304 B, granule-XOR swizzled
    __shared__ ushort ycp[2][CHK * YCS];    // 2 x 6272 B   (total 160000)

    const int tid = threadIdx.x;
    const int b   = blockIdx.x / NSTR;
    const int h0  = (blockIdx.x % NSTR) * RPB;
    const float* __restrict__ xb = x + (size_t)b * C_IN * HW;

    // ---- stage chunk t into xs[buf]: exactly 3 uniform loads/thread ----
    auto stage = [&](int t, int buf) {
        const int c0 = t * CHK;
#pragma unroll
        for (int k = 0; k < 3; ++k) {
            int d = tid + k * NT;            // 0..1535, no guard
            int q  = d & 15;
            int cr = d >> 4;
            int r  = cr % XR;
            int c  = cr / XR;
            int gh = h0 - 2 + r;
            bool ok = ((unsigned)gh < (unsigned)HH) && (q < 12);
            const float* src = ok ? (xb + (size_t)(c0 + c) * HW + gh * WW + q * 4) : zb;
            __builtin_amdgcn_global_load_lds(
                (const __attribute__((address_space(1))) unsigned int*)src,
                (__attribute__((address_space(3))) unsigned int*)(&xs[buf][0] + (size_t)d * 4),
                16, 0, 0);
        }
    };

    // ---- dwconv chunk t: 1536 tasks, pixel pair (w0, w0+24) ----
    auto dwconv = [&](int t) {
        const int c0 = t * CHK;
        const int buf = t & 1;
        ushort* yc = ycp[buf];
#pragma unroll
        for (int k = 0; k < 3; ++k) {
            int task = tid + k * NT;         // 0..1535, exact
            int c   = task / 192;
            int pt  = task % 192;
            int row = pt / 24;
            int w0  = pt % 24;               // lane-stride-1 column
            int cc  = c0 + c;
            const float* xb0 = &xs[buf][(size_t)(c * XR) * XROWF];
            float a0 = 0.f, a1 = 0.f;        // pixels (row,w0), (row,w0+24)
            if (cc < 32) {                   // 3x3
#pragma unroll
                for (int i = 0; i < 3; ++i) {
                    const float* xr = xb0 + (row + 1 + i) * XROWF;
                    float k0 = cen_t[cc * 9 + i * 3 + 0];
                    float k1 = cen_t[cc * 9 + i * 3 + 1];
                    float k2 = cen_t[cc * 9 + i * 3 + 2];
                    a0 += k0 * xr[(w0 - 1) & 63] + k1 * xr[w0] + k2 * xr[w0 + 1];
                    a1 += k0 * xr[w0 + 23] + k1 * xr[w0 + 24] + k2 * xr[w0 + 25];
                }
            } else if (cc < 56) {            // h
                int cd = cc - 32;
                const float* xr = xb0 + (row + 2) * XROWF;
#pragma unroll
                for (int i = 0; i < 5; ++i) {
                    float tt = dir_t[cd * 5 + i];
                    a0 += tt * xr[(w0 + i - 2) & 63];
                    a1 += tt * xr[w0 + 22 + i];
                }
            } else if (cc < 80) {            // v
                int cd = cc - 56;
#pragma unroll
                for (int i = 0; i < 5; ++i) {
                    float tt = dir_t[cd * 5 + i];
                    const float* xr = xb0 + (row + i) * XROWF;
                    a0 += tt * xr[w0];
                    a1 += tt * xr[w0 + 24];
                }
            } else if (cc < 104) {           // d1
                int cd = cc - 80;
#pragma unroll
                for (int i = 0; i < 5; ++i) {
                    float tt = dir_t[cd * 5 + i];
                    const float* xr = xb0 + (row + i) * XROWF;
                    a0 += tt * xr[(w0 + i - 2) & 63];
                    a1 += tt * xr[w0 + 22 + i];
                }
            } else {                         // d2
                int cd = cc - 104;
#pragma unroll
                for (int i = 0; i < 5; ++i) {
                    float tt = dir_t[cd * 5 + i];
                    const float* xr = xb0 + (row + i) * XROWF;
                    a0 += tt * xr[(w0 + 2 - i) & 63];
                    a1 += tt * xr[w0 + 26 - i];
                }
            }
            int p = row * 48 + w0;
            yc[c * YCS + p]      = f2bf(a0);
            yc[c * YCS + p + 24] = f2bf(a1);
        }
    };

    // ---- transpose chunk t: ycp[t&1][c][p] -> yT (granule-swizzled) ----
    auto transpose = [&](int t) {
        const ushort* src = ycp[t & 1];
#pragma unroll
        for (int k = 0; k < 3; ++k) {
            int task = tid + k * NT;         // 0..1535
            int cp = task & 3;
            int p  = task >> 2;
            ushort2 s;
            s.x = src[(cp * 2 + 0) * YCS + p];
            s.y = src[(cp * 2 + 1) * YCS + p];
            int gsw = t ^ (p & 7);           // granule of this chunk is t
            *(ushort2*)((char*)yT + p * 256 + (gsw << 4) + (cp << 2)) = s;
        }
    };

    // ================= counted-vmcnt pipeline =================
    stage(0, 0);
    SCHED_FENCE();
    for (int t = 0; t < NCHK - 1; ++t) {
        stage(t + 1, (t + 1) & 1);           // [A] 3 loads -> outstanding <=6
        SCHED_FENCE();
        WAIT_VM(3);                          // [B] stage(t) landed; t+1 in flight
        BAR();                               // [C] cross-wave visibility
        dwconv(t);
        if (t > 0) transpose(t - 1);
        WAIT_LGKM();                         // [F] publish ycp/yT ds-writes
        BAR();
    }
    // epilogue: t = NCHK-1, nothing left to stage
    WAIT_VM(0);
    BAR();
    dwconv(NCHK - 1);
    transpose(NCHK - 2);
    WAIT_LGKM();
    BAR();
    transpose(NCHK - 1);
    __syncthreads();

    // ================= MFMA mix: 8 waves, 2 passes x 64 out-ch =================
    const int l     = tid & 63;
    const int wv    = tid >> 6;              // 0..7
    const int ofr   = wv & 3;
    const int phalf = wv >> 2;
    float* __restrict__ ob = out + (size_t)b * C_OUT * HW + h0 * WW;

#pragma unroll
    for (int pass = 0; pass < 2; ++pass) {
        int o0 = pass * 64 + ofr * 16;
        bf16x8 afr[4];
#pragma unroll
        for (int kb = 0; kb < 4; ++kb)
            afr[kb] = *(const bf16x8*)(Mbf + (o0 + (l & 15)) * 128 + kb * 32 + (l >> 4) * 8);
        f32x4 acc[12] = {};
#pragma unroll
        for (int kb = 0; kb < 4; ++kb) {
            int g = kb * 4 + (l >> 4);
#pragma unroll
            for (int pf = 0; pf < 12; ++pf) {
                int p = (phalf * 12 + pf) * 16 + (l & 15);
                const bf16x8 bfr = *(const bf16x8*)((const char*)yT + p * 256 + ((g ^ (p & 7)) << 4));
                acc[pf] = __builtin_amdgcn_mfma_f32_16x16x32_bf16(afr[kb], bfr, acc[pf], 0, 0, 0);
            }
        }
#pragma unroll
        for (int pf = 0; pf < 12; ++pf) {
            int p = (phalf * 12 + pf) * 16 + (l & 15);
            int obase = o0 + (l >> 4) * 4;
#pragma unroll
            for (int r = 0; r < 4; ++r)
                ob[(size_t)(obase + r) * HW + p] = acc[pf][r];
        }
    }
}

// ======================= launcher =======================
extern "C" void kernel_launch(void* const* d_in, const int* in_sizes, int n_in,
                              void* d_out, int out_size, void* d_ws, size_t ws_size,
                              hipStream_t stream) {
    const float* x     = (const float*)d_in[0];
    const float* cen_t = (const float*)d_in[1];
    const float* dir_t = (const float*)d_in[2];
    const float* c2c   = (const float*)d_in[3];
    const float* p2c   = (const float*)d_in[4];
    const float* d2c   = (const float*)d_in[5];
    const float* c2d   = (const float*)d_in[6];
    const float* d2dW  = (const float*)d_in[7];
    float* out = (float*)d_out;

    ushort* Mbf = (ushort*)d_ws;                       // 32 KiB
    float*  zb  = (float*)((char*)d_ws + ZB_OFF);      // 16 B zero block

    hipMemsetAsync(zb, 0, 64, stream);                 // ws is poisoned each run
    build_M<<<64, 256, 0, stream>>>(c2c, p2c, d2c, c2d, d2dW, Mbf);
    dsc_fused<<<NB * NSTR, NT, 0, stream>>>(x, cen_t, dir_t, Mbf, zb, out);
}

// Round 15
// 102.054 us; speedup vs baseline: 1.1972x; 1.1972x over previous
//
#include <hip/hip_runtime.h>
#include <hip/hip_bf16.h>

// DirectionalSeparableConv2D — round 15: LDS-instruction-count attack.
// r13/r14 falsified latency-scheduling theories; arithmetic shows the wall is
// LDS-pipe issue throughput (~40us of scalar ds_read_b32 in dwconv alone).
// Rebuild on r10's skeleton (CHK=16, 8 chunks, 2 bar/chunk, NT=512):
//  * dwconv = 8-px tasks, window loads as 2-4 aligned ds_read_b128 per row
//    (&63 wrap lands in zero quads at both edges) -> ~1.7x fewer LDS cycles
//  * QR=17 (odd quad stride) -> b128 lane bank-quads ~18-distinct (<=3-way)
//  * ycp write = one b128 (8 ushorts)
//  * transpose: gather 8 ch -> one b128 write into granule-XOR-swizzled yT
//  * plain __syncthreads; DMA(t+1) overlaps transpose phase
// LDS 52224 + 98304 + 12544 = 163072 B.

namespace {
constexpr int HH = 48, WW = 48, HW = HH * WW;
constexpr int C_IN = 128, C_OUT = 128, NB = 128;
constexpr int RPB = 8;                  // stripe rows per block
constexpr int NSTR = HH / RPB;          // 6
constexpr int PIX = RPB * WW;           // 384
constexpr int NT = 512;
constexpr int CHK = 16;                 // channels per chunk
constexpr int NCHK = C_IN / CHK;        // 8
constexpr int XR = RPB + 4;             // 12 staged rows
constexpr int QR = 17;                  // quads per staged row (12 data + 5 zero)
constexpr int XROWF = QR * 4;           // 68 floats per row
constexpr int XQ = CHK * XR * QR;       // 3264 quads
constexpr int YCS = 392;                // ycp row stride (ushorts)
constexpr size_t M_BYTES = 128 * 128 * 2;
constexpr size_t ZB_OFF = M_BYTES;
}

typedef __attribute__((ext_vector_type(8))) short bf16x8;
typedef __attribute__((ext_vector_type(4))) float f32x4;

__device__ __forceinline__ ushort f2bf(float f) {
    __hip_bfloat16 h = __float2bfloat16(f);
    return *reinterpret_cast<ushort*>(&h);
}

// ======================= k0: build M_bf[o][c] (bf16) =======================
__global__ void build_M(const float* __restrict__ c2c, const float* __restrict__ p2c,
                        const float* __restrict__ d2c, const float* __restrict__ c2d,
                        const float* __restrict__ d2dW, ushort* __restrict__ Mbf) {
    int t = blockIdx.x * 256 + threadIdx.x;
    if (t >= 128 * 128) return;
    int o = t & 127, c = t >> 7;
    float v;
    if (o < 32) {
        if (c < 32)       v = c2c[o * 32 + c];
        else if (c < 56)  v = p2c[o * 24 + c - 32];
        else if (c < 80)  v = p2c[o * 24 + c - 56];
        else if (c < 104) v = d2c[o * 24 + c - 80];
        else              v = d2c[o * 24 + c - 104];
    } else {
        int g = (o - 32) / 24, oo = (o - 32) % 24;
        if (c < 32) v = c2d[oo * 32 + c];
        else {
            int gc = (c - 32) / 24, cc2 = (c - 32) % 24;
            v = (gc == g) ? d2dW[oo * 24 + cc2] : 0.f;
        }
    }
    Mbf[o * 128 + c] = f2bf(v);
}

// ======================= fused kernel =======================
__global__ __launch_bounds__(NT) void dsc_fused(
    const float* __restrict__ x,
    const float* __restrict__ cen_t,   // [32,3,3]
    const float* __restrict__ dir_t,   // [24,5]
    const ushort* __restrict__ Mbf,    // bf16 [128o][128c]
    const float* __restrict__ zb,      // 16B zero block
    float* __restrict__ out)
{
    __shared__ float  xs[XQ * 4];           // 52224 B  (single buffer)
    __shared__ ushort yT[PIX * 128];        // 98304 B, granule-XOR swizzled
    __shared__ ushort ycp[CHK * YCS];       // 12544 B       (total 163072)

    const int tid = threadIdx.x;
    const int b   = blockIdx.x / NSTR;
    const int h0  = (blockIdx.x % NSTR) * RPB;
    const float* __restrict__ xb = x + (size_t)b * C_IN * HW;

    // ---- stage chunk t: 3264 quads, dest linear ----
    auto stage = [&](int t) {
        const int c0 = t * CHK;
#pragma unroll
        for (int k = 0; k < 7; ++k) {
            int d = tid + k * NT;
            if (d < XQ) {
                int q  = d % QR;
                int cr = d / QR;
                int r  = cr % XR;
                int c  = cr / XR;
                int gh = h0 - 2 + r;
                bool ok = ((unsigned)gh < (unsigned)HH) && (q < 12);
                const float* src = ok ? (xb + (size_t)(c0 + c) * HW + gh * WW + q * 4) : zb;
                __builtin_amdgcn_global_load_lds(
                    (const __attribute__((address_space(1))) unsigned int*)src,
                    (__attribute__((address_space(3))) unsigned int*)(xs + (size_t)d * 4),
                    16, 0, 0);
            }
        }
    };

    // ---- dwconv chunk t: 768 eight-pixel tasks -> ycp (one b128/task) ----
    auto dwconv = [&](int t) {
        const int c0 = t * CHK;
#pragma unroll
        for (int k = 0; k < 2; ++k) {
            int task = tid + k * NT;
            if (task >= CHK * 48) break;
            int c   = task / 48;
            int pg  = task % 48;
            int row = pg & 7;
            int w0  = (pg >> 3) * 8;          // 0,8,..,40
            int cc  = c0 + c;
            const float* xr0 = xs + (size_t)(c * XR) * XROWF;
            float acc[8];
#pragma unroll
            for (int j = 0; j < 8; ++j) acc[j] = 0.f;

            if (cc < 32) {                     // 3x3: taps win[j+3..j+5]
#pragma unroll
                for (int i = 0; i < 3; ++i) {
                    const float* xr = xr0 + (row + 1 + i) * XROWF;
                    float4 A = *(const float4*)&xr[(w0 - 4) & 63];
                    float4 B = *(const float4*)&xr[w0];
                    float4 C = *(const float4*)&xr[w0 + 4];
                    float4 D = *(const float4*)&xr[(w0 + 8) & 63];
                    float win[16] = {A.x,A.y,A.z,A.w, B.x,B.y,B.z,B.w,
                                     C.x,C.y,C.z,C.w, D.x,D.y,D.z,D.w};
                    float k0 = cen_t[cc*9 + i*3 + 0];
                    float k1 = cen_t[cc*9 + i*3 + 1];
                    float k2 = cen_t[cc*9 + i*3 + 2];
#pragma unroll
                    for (int j = 0; j < 8; ++j)
                        acc[j] += k0*win[j+3] + k1*win[j+4] + k2*win[j+5];
                }
            } else if (cc < 56) {              // h: taps win[j+2+i]
                int cd = cc - 32;
                const float* xr = xr0 + (row + 2) * XROWF;
                float4 A = *(const float4*)&xr[(w0 - 4) & 63];
                float4 B = *(const float4*)&xr[w0];
                float4 C = *(const float4*)&xr[w0 + 4];
                float4 D = *(const float4*)&xr[(w0 + 8) & 63];
                float win[16] = {A.x,A.y,A.z,A.w, B.x,B.y,B.z,B.w,
                                 C.x,C.y,C.z,C.w, D.x,D.y,D.z,D.w};
#pragma unroll
                for (int i = 0; i < 5; ++i) {
                    float tt = dir_t[cd*5 + i];
#pragma unroll
                    for (int j = 0; j < 8; ++j) acc[j] += tt * win[j+2+i];
                }
            } else if (cc < 80) {              // v: 2 quads per row
                int cd = cc - 56;
#pragma unroll
                for (int i = 0; i < 5; ++i) {
                    const float* xr = xr0 + (row + i) * XROWF;
                    float4 B = *(const float4*)&xr[w0];
                    float4 C = *(const float4*)&xr[w0 + 4];
                    float w8[8] = {B.x,B.y,B.z,B.w, C.x,C.y,C.z,C.w};
                    float tt = dir_t[cd*5 + i];
#pragma unroll
                    for (int j = 0; j < 8; ++j) acc[j] += tt * w8[j];
                }
            } else {                           // d1 / d2
                int cd  = (cc < 104) ? cc - 80 : cc - 104;
                bool d1 = (cc < 104);
#pragma unroll
                for (int i = 0; i < 5; ++i) {
                    const float* xr = xr0 + (row + i) * XROWF;
                    float4 A = *(const float4*)&xr[(w0 - 4) & 63];
                    float4 B = *(const float4*)&xr[w0];
                    float4 C = *(const float4*)&xr[w0 + 4];
                    float4 D = *(const float4*)&xr[(w0 + 8) & 63];
                    float win[16] = {A.x,A.y,A.z,A.w, B.x,B.y,B.z,B.w,
                                     C.x,C.y,C.z,C.w, D.x,D.y,D.z,D.w};
                    float tt = dir_t[cd*5 + i];
                    if (d1) {
#pragma unroll
                        for (int j = 0; j < 8; ++j) acc[j] += tt * win[j+2+i];
                    } else {
#pragma unroll
                        for (int j = 0; j < 8; ++j) acc[j] += tt * win[j+6-i];
                    }
                }
            }

            union { ushort us[8]; uint4 v4; } s;
#pragma unroll
            for (int j = 0; j < 8; ++j) s.us[j] = f2bf(acc[j]);
            *(uint4*)&ycp[c * YCS + row * 48 + w0] = s.v4;   // 16B aligned
        }
    };

    // ---- transpose chunk t: gather 8 ch of one px -> b128 into yT ----
    auto transpose = [&](int t) {
#pragma unroll
        for (int k = 0; k < 2; ++k) {
            int task = tid + k * NT;
            if (task >= 2 * PIX) break;
            int gg = task / PIX;               // chunk-local granule 0..1
            int p  = task % PIX;
            int g  = t * 2 + gg;               // global granule 0..15
            union { ushort us[8]; uint4 v4; } s;
#pragma unroll
            for (int j = 0; j < 8; ++j) s.us[j] = ycp[(gg * 8 + j) * YCS + p];
            int byte = p * 256 + ((g ^ (p & 7)) << 4);
            *(uint4*)((char*)yT + byte) = s.v4;
        }
    };

    // ================= channel-streamed dwconv =================
    stage(0);
    __syncthreads();
    for (int t = 0; t < NCHK; ++t) {
        dwconv(t);
        __syncthreads();                       // xs reads + ycp writes done
        if (t + 1 < NCHK) stage(t + 1);        // DMA overlaps transpose
        transpose(t);
        __syncthreads();                       // DMA drained; ycp free
    }

    // ================= MFMA mix: 8 waves, 2 passes x 64 out-ch =================
    const int l     = tid & 63;
    const int wv    = tid >> 6;                // 0..7
    const int ofr   = wv & 3;
    const int phalf = wv >> 2;
    float* __restrict__ ob = out + (size_t)b * C_OUT * HW + h0 * WW;

#pragma unroll
    for (int pass = 0; pass < 2; ++pass) {
        int o0 = pass * 64 + ofr * 16;
        bf16x8 afr[4];
#pragma unroll
        for (int kb = 0; kb < 4; ++kb)
            afr[kb] = *(const bf16x8*)(Mbf + (o0 + (l & 15)) * 128 + kb * 32 + (l >> 4) * 8);
        f32x4 acc[12] = {};
#pragma unroll
        for (int kb = 0; kb < 4; ++kb) {
            int g = kb * 4 + (l >> 4);
#pragma unroll
            for (int pf = 0; pf < 12; ++pf) {
                int p = (phalf * 12 + pf) * 16 + (l & 15);
                const bf16x8 bfr = *(const bf16x8*)((const char*)yT + p * 256 + ((g ^ (p & 7)) << 4));
                acc[pf] = __builtin_amdgcn_mfma_f32_16x16x32_bf16(afr[kb], bfr, acc[pf], 0, 0, 0);
            }
        }
#pragma unroll
        for (int pf = 0; pf < 12; ++pf) {
            int p = (phalf * 12 + pf) * 16 + (l & 15);
            int obase = o0 + (l >> 4) * 4;
#pragma unroll
            for (int r = 0; r < 4; ++r)
                ob[(size_t)(obase + r) * HW + p] = acc[pf][r];
        }
    }
}

// ======================= launcher =======================
extern "C" void kernel_launch(void* const* d_in, const int* in_sizes, int n_in,
                              void* d_out, int out_size, void* d_ws, size_t ws_size,
                              hipStream_t stream) {
    const float* x     = (const float*)d_in[0];
    const float* cen_t = (const float*)d_in[1];
    const float* dir_t = (const float*)d_in[2];
    const float* c2c   = (const float*)d_in[3];
    const float* p2c   = (const float*)d_in[4];
    const float* d2c   = (const float*)d_in[5];
    const float* c2d   = (const float*)d_in[6];
    const float* d2dW  = (const float*)d_in[7];
    float* out = (float*)d_out;

    ushort* Mbf = (ushort*)d_ws;                       // 32 KiB
    float*  zb  = (float*)((char*)d_ws + ZB_OFF);      // 16 B zero block

    hipMemsetAsync(zb, 0, 64, stream);                 // ws is poisoned each run
    build_M<<<64, 256, 0, stream>>>(c2c, p2c, d2c, c2d, d2dW, Mbf);
    dsc_fused<<<NB * NSTR, NT, 0, stream>>>(x, cen_t, dir_t, Mbf, zb, out);
}

// Round 18
// 97.710 us; speedup vs baseline: 1.2504x; 1.0445x over previous
//
#include <hip/hip_runtime.h>
#include <hip/hip_bf16.h>

// DirectionalSeparableConv2D — round 18: r15 (known-pass, 102us) + bijective
// XCD blockIdx swizzle (T1). r16/r17's 2-blocks/CU restructure failed absmax
// twice (0.072/0.091) with mappings that verify correct on paper — abandoned
// per rigor discipline (unexplained failure != shippable).
// Swizzle: grid 768 = 8 XCDs x 96 -> bid=(orig%8)*96+orig/8 (bijection;
// correctness-neutral). Groups same-image stripes (shared halo + Mbf) per XCD.

namespace {
constexpr int HH = 48, WW = 48, HW = HH * WW;
constexpr int C_IN = 128, C_OUT = 128, NB = 128;
constexpr int RPB = 8;                  // stripe rows per block
constexpr int NSTR = HH / RPB;          // 6
constexpr int PIX = RPB * WW;           // 384
constexpr int NT = 512;
constexpr int CHK = 16;                 // channels per chunk
constexpr int NCHK = C_IN / CHK;        // 8
constexpr int XR = RPB + 4;             // 12 staged rows
constexpr int QR = 17;                  // quads per staged row (12 data + 5 zero)
constexpr int XROWF = QR * 4;           // 68 floats per row
constexpr int XQ = CHK * XR * QR;       // 3264 quads
constexpr int YCS = 392;                // ycp row stride (ushorts)
constexpr int NBLK = NB * NSTR;         // 768 = 8 * 96
constexpr size_t M_BYTES = 128 * 128 * 2;
constexpr size_t ZB_OFF = M_BYTES;
}

typedef __attribute__((ext_vector_type(8))) short bf16x8;
typedef __attribute__((ext_vector_type(4))) float f32x4;

__device__ __forceinline__ ushort f2bf(float f) {
    __hip_bfloat16 h = __float2bfloat16(f);
    return *reinterpret_cast<ushort*>(&h);
}

// ======================= k0: build M_bf[o][c] (bf16) =======================
__global__ void build_M(const float* __restrict__ c2c, const float* __restrict__ p2c,
                        const float* __restrict__ d2c, const float* __restrict__ c2d,
                        const float* __restrict__ d2dW, ushort* __restrict__ Mbf) {
    int t = blockIdx.x * 256 + threadIdx.x;
    if (t >= 128 * 128) return;
    int o = t & 127, c = t >> 7;
    float v;
    if (o < 32) {
        if (c < 32)       v = c2c[o * 32 + c];
        else if (c < 56)  v = p2c[o * 24 + c - 32];
        else if (c < 80)  v = p2c[o * 24 + c - 56];
        else if (c < 104) v = d2c[o * 24 + c - 80];
        else              v = d2c[o * 24 + c - 104];
    } else {
        int g = (o - 32) / 24, oo = (o - 32) % 24;
        if (c < 32) v = c2d[oo * 32 + c];
        else {
            int gc = (c - 32) / 24, cc2 = (c - 32) % 24;
            v = (gc == g) ? d2dW[oo * 24 + cc2] : 0.f;
        }
    }
    Mbf[o * 128 + c] = f2bf(v);
}

// ======================= fused kernel =======================
__global__ __launch_bounds__(NT) void dsc_fused(
    const float* __restrict__ x,
    const float* __restrict__ cen_t,   // [32,3,3]
    const float* __restrict__ dir_t,   // [24,5]
    const ushort* __restrict__ Mbf,    // bf16 [128o][128c]
    const float* __restrict__ zb,      // 16B zero block
    float* __restrict__ out)
{
    __shared__ float  xs[XQ * 4];           // 52224 B  (single buffer)
    __shared__ ushort yT[PIX * 128];        // 98304 B, granule-XOR swizzled
    __shared__ ushort ycp[CHK * YCS];       // 12544 B       (total 163072)

    const int tid = threadIdx.x;
    // Bijective XCD swizzle: 768 = 8 * 96 exactly.
    const int bid = (blockIdx.x & 7) * (NBLK / 8) + (blockIdx.x >> 3);
    const int b   = bid / NSTR;
    const int h0  = (bid % NSTR) * RPB;
    const float* __restrict__ xb = x + (size_t)b * C_IN * HW;

    // ---- stage chunk t: 3264 quads, dest linear ----
    auto stage = [&](int t) {
        const int c0 = t * CHK;
#pragma unroll
        for (int k = 0; k < 7; ++k) {
            int d = tid + k * NT;
            if (d < XQ) {
                int q  = d % QR;
                int cr = d / QR;
                int r  = cr % XR;
                int c  = cr / XR;
                int gh = h0 - 2 + r;
                bool ok = ((unsigned)gh < (unsigned)HH) && (q < 12);
                const float* src = ok ? (xb + (size_t)(c0 + c) * HW + gh * WW + q * 4) : zb;
                __builtin_amdgcn_global_load_lds(
                    (const __attribute__((address_space(1))) unsigned int*)src,
                    (__attribute__((address_space(3))) unsigned int*)(xs + (size_t)d * 4),
                    16, 0, 0);
            }
        }
    };

    // ---- dwconv chunk t: 768 eight-pixel tasks -> ycp (one b128/task) ----
    auto dwconv = [&](int t) {
        const int c0 = t * CHK;
#pragma unroll
        for (int k = 0; k < 2; ++k) {
            int task = tid + k * NT;
            if (task >= CHK * 48) break;
            int c   = task / 48;
            int pg  = task % 48;
            int row = pg & 7;
            int w0  = (pg >> 3) * 8;          // 0,8,..,40
            int cc  = c0 + c;
            const float* xr0 = xs + (size_t)(c * XR) * XROWF;
            float acc[8];
#pragma unroll
            for (int j = 0; j < 8; ++j) acc[j] = 0.f;

            if (cc < 32) {                     // 3x3: taps win[j+3..j+5]
#pragma unroll
                for (int i = 0; i < 3; ++i) {
                    const float* xr = xr0 + (row + 1 + i) * XROWF;
                    float4 A = *(const float4*)&xr[(w0 - 4) & 63];
                    float4 B = *(const float4*)&xr[w0];
                    float4 C = *(const float4*)&xr[w0 + 4];
                    float4 D = *(const float4*)&xr[(w0 + 8) & 63];
                    float win[16] = {A.x,A.y,A.z,A.w, B.x,B.y,B.z,B.w,
                                     C.x,C.y,C.z,C.w, D.x,D.y,D.z,D.w};
                    float k0 = cen_t[cc*9 + i*3 + 0];
                    float k1 = cen_t[cc*9 + i*3 + 1];
                    float k2 = cen_t[cc*9 + i*3 + 2];
#pragma unroll
                    for (int j = 0; j < 8; ++j)
                        acc[j] += k0*win[j+3] + k1*win[j+4] + k2*win[j+5];
                }
            } else if (cc < 56) {              // h: taps win[j+2+i]
                int cd = cc - 32;
                const float* xr = xr0 + (row + 2) * XROWF;
                float4 A = *(const float4*)&xr[(w0 - 4) & 63];
                float4 B = *(const float4*)&xr[w0];
                float4 C = *(const float4*)&xr[w0 + 4];
                float4 D = *(const float4*)&xr[(w0 + 8) & 63];
                float win[16] = {A.x,A.y,A.z,A.w, B.x,B.y,B.z,B.w,
                                 C.x,C.y,C.z,C.w, D.x,D.y,D.z,D.w};
#pragma unroll
                for (int i = 0; i < 5; ++i) {
                    float tt = dir_t[cd*5 + i];
#pragma unroll
                    for (int j = 0; j < 8; ++j) acc[j] += tt * win[j+2+i];
                }
            } else if (cc < 80) {              // v: 2 quads per row
                int cd = cc - 56;
#pragma unroll
                for (int i = 0; i < 5; ++i) {
                    const float* xr = xr0 + (row + i) * XROWF;
                    float4 B = *(const float4*)&xr[w0];
                    float4 C = *(const float4*)&xr[w0 + 4];
                    float w8[8] = {B.x,B.y,B.z,B.w, C.x,C.y,C.z,C.w};
                    float tt = dir_t[cd*5 + i];
#pragma unroll
                    for (int j = 0; j < 8; ++j) acc[j] += tt * w8[j];
                }
            } else {                           // d1 / d2
                int cd  = (cc < 104) ? cc - 80 : cc - 104;
                bool d1 = (cc < 104);
#pragma unroll
                for (int i = 0; i < 5; ++i) {
                    const float* xr = xr0 + (row + i) * XROWF;
                    float4 A = *(const float4*)&xr[(w0 - 4) & 63];
                    float4 B = *(const float4*)&xr[w0];
                    float4 C = *(const float4*)&xr[w0 + 4];
                    float4 D = *(const float4*)&xr[(w0 + 8) & 63];
                    float win[16] = {A.x,A.y,A.z,A.w, B.x,B.y,B.z,B.w,
                                     C.x,C.y,C.z,C.w, D.x,D.y,D.z,D.w};
                    float tt = dir_t[cd*5 + i];
                    if (d1) {
#pragma unroll
                        for (int j = 0; j < 8; ++j) acc[j] += tt * win[j+2+i];
                    } else {
#pragma unroll
                        for (int j = 0; j < 8; ++j) acc[j] += tt * win[j+6-i];
                    }
                }
            }

            union { ushort us[8]; uint4 v4; } s;
#pragma unroll
            for (int j = 0; j < 8; ++j) s.us[j] = f2bf(acc[j]);
            *(uint4*)&ycp[c * YCS + row * 48 + w0] = s.v4;   // 16B aligned
        }
    };

    // ---- transpose chunk t: gather 8 ch of one px -> b128 into yT ----
    auto transpose = [&](int t) {
#pragma unroll
        for (int k = 0; k < 2; ++k) {
            int task = tid + k * NT;
            if (task >= 2 * PIX) break;
            int gg = task / PIX;               // chunk-local granule 0..1
            int p  = task % PIX;
            int g  = t * 2 + gg;               // global granule 0..15
            union { ushort us[8]; uint4 v4; } s;
#pragma unroll
            for (int j = 0; j < 8; ++j) s.us[j] = ycp[(gg * 8 + j) * YCS + p];
            int byte = p * 256 + ((g ^ (p & 7)) << 4);
            *(uint4*)((char*)yT + byte) = s.v4;
        }
    };

    // ================= channel-streamed dwconv =================
    stage(0);
    __syncthreads();
    for (int t = 0; t < NCHK; ++t) {
        dwconv(t);
        __syncthreads();                       // xs reads + ycp writes done
        if (t + 1 < NCHK) stage(t + 1);        // DMA overlaps transpose
        transpose(t);
        __syncthreads();                       // DMA drained; ycp free
    }

    // ================= MFMA mix: 8 waves, 2 passes x 64 out-ch =================
    const int l     = tid & 63;
    const int wv    = tid >> 6;                // 0..7
    const int ofr   = wv & 3;
    const int phalf = wv >> 2;
    float* __restrict__ ob = out + (size_t)b * C_OUT * HW + h0 * WW;

#pragma unroll
    for (int pass = 0; pass < 2; ++pass) {
        int o0 = pass * 64 + ofr * 16;
        bf16x8 afr[4];
#pragma unroll
        for (int kb = 0; kb < 4; ++kb)
            afr[kb] = *(const bf16x8*)(Mbf + (o0 + (l & 15)) * 128 + kb * 32 + (l >> 4) * 8);
        f32x4 acc[12] = {};
#pragma unroll
        for (int kb = 0; kb < 4; ++kb) {
            int g = kb * 4 + (l >> 4);
#pragma unroll
            for (int pf = 0; pf < 12; ++pf) {
                int p = (phalf * 12 + pf) * 16 + (l & 15);
                const bf16x8 bfr = *(const bf16x8*)((const char*)yT + p * 256 + ((g ^ (p & 7)) << 4));
                acc[pf] = __builtin_amdgcn_mfma_f32_16x16x32_bf16(afr[kb], bfr, acc[pf], 0, 0, 0);
            }
        }
#pragma unroll
        for (int pf = 0; pf < 12; ++pf) {
            int p = (phalf * 12 + pf) * 16 + (l & 15);
            int obase = o0 + (l >> 4) * 4;
#pragma unroll
            for (int r = 0; r < 4; ++r)
                ob[(size_t)(obase + r) * HW + p] = acc[pf][r];
        }
    }
}

// ======================= launcher =======================
extern "C" void kernel_launch(void* const* d_in, const int* in_sizes, int n_in,
                              void* d_out, int out_size, void* d_ws, size_t ws_size,
                              hipStream_t stream) {
    const float* x     = (const float*)d_in[0];
    const float* cen_t = (const float*)d_in[1];
    const float* dir_t = (const float*)d_in[2];
    const float* c2c   = (const float*)d_in[3];
    const float* p2c   = (const float*)d_in[4];
    const float* d2c   = (const float*)d_in[5];
    const float* c2d   = (const float*)d_in[6];
    const float* d2dW  = (const float*)d_in[7];
    float* out = (float*)d_out;

    ushort* Mbf = (ushort*)d_ws;                       // 32 KiB
    float*  zb  = (float*)((char*)d_ws + ZB_OFF);      // 16 B zero block

    hipMemsetAsync(zb, 0, 64, stream);                 // ws is poisoned each run
    build_M<<<64, 256, 0, stream>>>(c2c, p2c, d2c, c2d, d2dW, Mbf);
    dsc_fused<<<NBLK, NT, 0, stream>>>(x, cen_t, dir_t, Mbf, zb, out);
}